// Round 1
// baseline (425.804 us; speedup 1.0000x reference)
//
#include <hip/hip_runtime.h>
#include <math.h>

#define D_MODEL 1024
#define N_STATE 64
#define BATCH   16
#define SEQ     1024
#define CS      16          // scan steps per LDS chunk
#define SEGLEN  512         // steps stored per segment
#define WARM    64          // warmup steps for segment 1 (0.7311^64 ~ 2e-9)
#define SAT_T   1.0001f     // saturation margin (covers fp32 rounding)

__device__ __forceinline__ float sigmoidf_dev(float v) {
    return 1.0f / (1.0f + expf(-v));
}

// DPP add: v += v[partner] within an aligned 16-lane row. Pure VALU, no LDS.
// 0xB1 = quad_perm [1,0,3,2] (xor1), 0x4E = quad_perm [2,3,0,1] (xor2),
// 0x141 = row_half_mirror (acts as xor4 on quad-uniform values),
// 0x140 = row_mirror (acts as xor8 on half-row-uniform values).
template<int CTRL>
__device__ __forceinline__ float dpp_add(float v) {
    int s = __builtin_amdgcn_update_dpp(0, __float_as_int(v), CTRL, 0xF, 0xF, true);
    return v + __int_as_float(s);
}

template<int CTRL>
__device__ __forceinline__ float dpp_min(float v) {
    int s = __builtin_amdgcn_update_dpp(0, __float_as_int(v), CTRL, 0xF, 0xF, true);
    return fminf(v, __int_as_float(s));
}

#define CLAMP01(v) __builtin_amdgcn_fmed3f((v), 0.0f, 1.0f)

// ---------------------------------------------------------------------------
// k0: precompute sigmoid(A) [D,N], sigmoid(W_B)^T -> BwT [D,N],
//     sigmoid(W_C) [D,N], sigmoid(gamma) [D]
// ---------------------------------------------------------------------------
__global__ __launch_bounds__(256) void k0_precompute(
        const float* __restrict__ A, const float* __restrict__ W_B,
        const float* __restrict__ W_C, const float* __restrict__ gamma,
        float* __restrict__ A_sig, float* __restrict__ BwT,
        float* __restrict__ Cs, float* __restrict__ gs) {
    int i = blockIdx.x * 256 + threadIdx.x;
    if (i < D_MODEL * N_STATE) {
        A_sig[i] = sigmoidf_dev(A[i]);
        Cs[i]    = sigmoidf_dev(W_C[i]);
        int d = i >> 6, n = i & 63;                  // i = d*64 + n
        BwT[i] = sigmoidf_dev(W_B[n * D_MODEL + d]); // W_B is [N, D]
        if (i < D_MODEL) gs[i] = sigmoidf_dev(gamma[i]);
    }
}

// ---------------------------------------------------------------------------
// k1: bt[m][n] = sum_d x[m][d] * BwT[d][n]  (M=16384, K=1024, N=64, fp32)
// grid 512 (2 blocks/CU), block 256. Mtile=32, Ntile=64, Ktile=32.
// 8 outputs/thread (2m x 4n). Double-buffered LDS + register prefetch.
// Epilogue additionally emits btmin[m] = min_n bt[m][n] (DPP row-min) for
// k2's saturation fast path.
// ---------------------------------------------------------------------------
__global__ __launch_bounds__(256) void k1_bt_gemm(
        const float* __restrict__ x, const float* __restrict__ BwT,
        float* __restrict__ bt, float* __restrict__ btmin) {
    __shared__ float xs[2][32][34];   // [buf][k][m], +2 pad
    __shared__ float bs[2][32][64];   // [buf][k][n]

    const int t  = threadIdx.x;
    const int r  = t >> 4;            // 0..15 -> m rows r*2, r*2+1
    const int c  = t & 15;            // 0..15 -> n quad c*4
    const int m0 = blockIdx.x * 32;

    const int mr  = t >> 3;           // 0..31 (x staging row)
    const int kc4 = (t & 7) * 4;      // 0..28 (x staging k quad)

    float acc[2][4];
#pragma unroll
    for (int i = 0; i < 2; ++i)
#pragma unroll
        for (int j = 0; j < 4; ++j) acc[i][j] = 0.0f;

    {
        float4 xv = *(const float4*)(x + (size_t)(m0 + mr) * D_MODEL + kc4);
        float4 b0 = *(const float4*)(BwT + t * 4);
        float4 b1 = *(const float4*)(BwT + 1024 + t * 4);
        xs[0][kc4 + 0][mr] = xv.x;
        xs[0][kc4 + 1][mr] = xv.y;
        xs[0][kc4 + 2][mr] = xv.z;
        xs[0][kc4 + 3][mr] = xv.w;
        *(float4*)(&bs[0][0][0] + t * 4)        = b0;
        *(float4*)(&bs[0][0][0] + 1024 + t * 4) = b1;
    }
    __syncthreads();

    for (int kc = 0; kc < 32; ++kc) {
        const int p = kc & 1;
        float4 xv, b0, b1;
        const bool more = (kc + 1 < 32);
        if (more) {
            const int k0 = (kc + 1) * 32;
            xv = *(const float4*)(x + (size_t)(m0 + mr) * D_MODEL + k0 + kc4);
            b0 = *(const float4*)(BwT + (size_t)k0 * N_STATE + t * 4);
            b1 = *(const float4*)(BwT + (size_t)k0 * N_STATE + 1024 + t * 4);
        }
#pragma unroll
        for (int kk = 0; kk < 32; ++kk) {
            float2 ap = *(const float2*)(&xs[p][kk][r * 2]);
            float4 bq = *(const float4*)(&bs[p][kk][c * 4]);
            acc[0][0] = fmaf(ap.x, bq.x, acc[0][0]);
            acc[0][1] = fmaf(ap.x, bq.y, acc[0][1]);
            acc[0][2] = fmaf(ap.x, bq.z, acc[0][2]);
            acc[0][3] = fmaf(ap.x, bq.w, acc[0][3]);
            acc[1][0] = fmaf(ap.y, bq.x, acc[1][0]);
            acc[1][1] = fmaf(ap.y, bq.y, acc[1][1]);
            acc[1][2] = fmaf(ap.y, bq.z, acc[1][2]);
            acc[1][3] = fmaf(ap.y, bq.w, acc[1][3]);
        }
        if (more) {
            const int q = 1 - p;
            xs[q][kc4 + 0][mr] = xv.x;
            xs[q][kc4 + 1][mr] = xv.y;
            xs[q][kc4 + 2][mr] = xv.z;
            xs[q][kc4 + 3][mr] = xv.w;
            *(float4*)(&bs[q][0][0] + t * 4)        = b0;
            *(float4*)(&bs[q][0][0] + 1024 + t * 4) = b1;
        }
        __syncthreads();
    }

#pragma unroll
    for (int i = 0; i < 2; ++i) {
        float4 o = make_float4(acc[i][0], acc[i][1], acc[i][2], acc[i][3]);
        *(float4*)(&bt[(size_t)(m0 + r * 2 + i) * N_STATE + c * 4]) = o;
    }

    // btmin epilogue: per-thread min of its 4 n's, then DPP row-min over the
    // 16 lanes sharing r (lanes (r&3)*16 .. +15 within the wave, aligned).
    float bm0 = fminf(fminf(acc[0][0], acc[0][1]), fminf(acc[0][2], acc[0][3]));
    float bm1 = fminf(fminf(acc[1][0], acc[1][1]), fminf(acc[1][2], acc[1][3]));
    bm0 = dpp_min<0xB1>(bm0); bm0 = dpp_min<0x4E>(bm0);
    bm0 = dpp_min<0x141>(bm0); bm0 = dpp_min<0x140>(bm0);
    bm1 = dpp_min<0xB1>(bm1); bm1 = dpp_min<0x4E>(bm1);
    bm1 = dpp_min<0x141>(bm1); bm1 = dpp_min<0x140>(bm1);
    if (c == 0) {
        btmin[m0 + r * 2]     = bm0;
        btmin[m0 + r * 2 + 1] = bm1;
    }
}

// ---------------------------------------------------------------------------
// k2: sequential scan, time-segmented 2x. grid 2048 = 16 batch x 64 dgroup x
// 2 segments -> 8 blocks/CU, 32 waves/CU.
// Saturation fast path: if min_n bt[s][n] * x[s][d] >= 1+eps then EVERY
// h-state clamps to exactly 1.0f this step regardless of history, and the
// step's output is exactly csum[d] = sum_n Cs[d][n] (same fma/add/DPP order
// as the slow path with h==1, so bitwise identical). A per-chunk wave vote
// (min over 16 steps x 4 chains) skips whole chunks (~78%); mixed chunks
// re-vote per step (~98% fast). Slow steps run the exact original update +
// straight 4-stage DPP reduction (no pipeline lag needed anymore).
// ---------------------------------------------------------------------------
__global__ __launch_bounds__(256, 8) void k2_scan(
        const float* __restrict__ x, const float* __restrict__ bt,
        const float* __restrict__ btmin,
        const float* __restrict__ A_sig, const float* __restrict__ Cs,
        float* __restrict__ y_raw) {
    const int t    = threadIdx.x;
    const int lane = t & 63;
    const int wv   = t >> 6;
    const int nq   = lane & 15;            // n-quad -> n = nq*4
    const int cl   = wv * 4 + (lane >> 4); // chain within block, 0..15
    const int bid  = blockIdx.x;
    const int seg  = bid & 1;
    const int dg   = (bid >> 1) & 63;
    const int b    = bid >> 7;
    const int d0   = dg * 16;
    const int d    = d0 + cl;

    const int nWarm  = seg ? (WARM / CS) : 0;     // 4 or 0
    const int nTot   = nWarm + (SEGLEN / CS);     // 36 or 32
    const int sStart = seg * SEGLEN - nWarm * CS; // 0 or 448

    __shared__ __align__(16) float lbt[2][CS * 64];   // 2 x 4 KB bt tile
    __shared__ __align__(16) float lxT[2][16 * CS];   // 2 x 1 KB, TRANSPOSED [chain][step]
    __shared__ __align__(16) float lbm[2][CS];        // 2 x 64 B btmin (clamped >= 0)

    const float4 av = *(const float4*)(A_sig + (size_t)d * N_STATE + nq * 4);
    const float4 cv = *(const float4*)(Cs    + (size_t)d * N_STATE + nq * 4);

    // csum[d] = sum_n Cs[d][n], computed in EXACTLY the slow-path op order
    // with h==1: fmaf(1,cx,1*cy)+fmaf(1,cz,1*cw) == (cx+cy)+(cz+cw), then
    // the same DPP tree. All 16 lanes of a row end up with the row sum.
    float csum;
    {
        float s = (cv.x + cv.y) + (cv.z + cv.w);
        s = dpp_add<0xB1>(s);
        s = dpp_add<0x4E>(s);
        s = dpp_add<0x141>(s);
        s = dpp_add<0x140>(s);
        csum = s;
    }

    float h0 = 0.f, h1 = 0.f, h2 = 0.f, h3 = 0.f;

    const float* btp  = bt    + (size_t)b * SEQ * N_STATE + (size_t)sStart * N_STATE;
    const float* btmp = btmin + (size_t)b * SEQ + sStart;
    const float* xpp  = x + (size_t)b * SEQ * D_MODEL + (size_t)sStart * D_MODEL + d0;
    float* ystore = y_raw + (size_t)b * SEQ * D_MODEL + (size_t)seg * SEGLEN * D_MODEL + d;

    const int xst = t >> 4;          // staging: step 0..15
    const int xdd = t & 15;          // staging: chain

    // stage chunk 0 into buf 0
    {
        float4 b4 = *(const float4*)(btp + t * 4);
        float  xv = xpp[(size_t)xst * D_MODEL + xdd];
        *(float4*)(&lbt[0][t * 4]) = b4;
        lxT[0][xdd * CS + xst] = xv;
        // clamp btmin at 0: guarantees (pm >= SAT_T) => btmin > 0 AND xt > 0,
        // so bv*xt >= btmin*xt >= SAT_T holds for every n (sign-safe).
        if (t < CS) lbm[0][t] = fmaxf(btmp[t], 0.f);
    }
    btp  += CS * N_STATE;
    btmp += CS;
    xpp  += (size_t)CS * D_MODEL;
    __syncthreads();

    for (int ch = 0; ch < nTot; ++ch) {
        const int p = ch & 1;
        float4 nb; float nx; float nm;
        const bool more = (ch + 1 < nTot);
        if (more) {
            nb = *(const float4*)(btp + t * 4);
            nx = xpp[(size_t)xst * D_MODEL + xdd];
            nm = (t < CS) ? fmaxf(btmp[t], 0.f) : 0.f;
            btp  += CS * N_STATE;
            btmp += CS;
            xpp  += (size_t)CS * D_MODEL;
        }

        const float* Lb = lbt[p];
        const float* Lx = &lxT[p][cl * CS];   // this lane's chain, 16 steps, 16B-aligned
        const float* Lm = lbm[p];

        // chunk-level saturation vote: min over 16 steps of xt*btmin (per row)
        float mm;
        {
            float4 x0 = *(const float4*)(Lx + 0);
            float4 x1 = *(const float4*)(Lx + 4);
            float4 x2 = *(const float4*)(Lx + 8);
            float4 x3 = *(const float4*)(Lx + 12);
            float4 m0 = *(const float4*)(Lm + 0);
            float4 m1 = *(const float4*)(Lm + 4);
            float4 m2 = *(const float4*)(Lm + 8);
            float4 m3 = *(const float4*)(Lm + 12);
            float p0 = fminf(fminf(x0.x * m0.x, x0.y * m0.y), fminf(x0.z * m0.z, x0.w * m0.w));
            float p1 = fminf(fminf(x1.x * m1.x, x1.y * m1.y), fminf(x1.z * m1.z, x1.w * m1.w));
            float p2 = fminf(fminf(x2.x * m2.x, x2.y * m2.y), fminf(x2.z * m2.z, x2.w * m2.w));
            float p3 = fminf(fminf(x3.x * m3.x, x3.y * m3.y), fminf(x3.z * m3.z, x3.w * m3.w));
            mm = fminf(fminf(p0, p1), fminf(p2, p3));
        }
        const bool allfast = (__all(mm >= SAT_T) != 0);

        if (ch < nWarm) {
            if (allfast) {
                h0 = h1 = h2 = h3 = 1.f;   // exact: every step in chunk clamps to 1
            } else {
#pragma unroll
                for (int i = 0; i < CS; ++i) {
                    const float xt = Lx[i];
                    if (__all(xt * Lm[i] >= SAT_T)) {
                        h0 = h1 = h2 = h3 = 1.f;
                    } else {
                        const float4 bv = *(const float4*)(Lb + i * 64 + nq * 4);
                        h0 = CLAMP01(fmaf(h0, av.x, bv.x * xt));
                        h1 = CLAMP01(fmaf(h1, av.y, bv.y * xt));
                        h2 = CLAMP01(fmaf(h2, av.z, bv.z * xt));
                        h3 = CLAMP01(fmaf(h3, av.w, bv.w * xt));
                    }
                }
            }
        } else {
            if (allfast) {
                h0 = h1 = h2 = h3 = 1.f;
                // 16 steps' outputs are all csum: lane nq stores step nq
                // (addresses within the block cover d0..d0+15 per step; L2
                // merges the 4B stores into full lines).
                ystore[(size_t)nq * D_MODEL] = csum;
            } else {
#pragma unroll
                for (int i = 0; i < CS; ++i) {
                    const float xt = Lx[i];
                    if (__all(xt * Lm[i] >= SAT_T)) {
                        h0 = h1 = h2 = h3 = 1.f;
                        if (nq == 0) ystore[(size_t)i * D_MODEL] = csum;
                    } else {
                        const float4 bv = *(const float4*)(Lb + i * 64 + nq * 4);
                        h0 = CLAMP01(fmaf(h0, av.x, bv.x * xt));
                        h1 = CLAMP01(fmaf(h1, av.y, bv.y * xt));
                        h2 = CLAMP01(fmaf(h2, av.z, bv.z * xt));
                        h3 = CLAMP01(fmaf(h3, av.w, bv.w * xt));
                        float y = fmaf(h0, cv.x, h1 * cv.y) + fmaf(h2, cv.z, h3 * cv.w);
                        y = dpp_add<0xB1>(y);
                        y = dpp_add<0x4E>(y);
                        y = dpp_add<0x141>(y);
                        y = dpp_add<0x140>(y);
                        if (nq == 0) ystore[(size_t)i * D_MODEL] = y;
                    }
                }
            }
            ystore += (size_t)CS * D_MODEL;
        }

        if (more) {
            const int q = 1 - p;
            *(float4*)(&lbt[q][t * 4]) = nb;
            lxT[q][xdd * CS + xst] = nx;
            if (t < CS) lbm[q][t] = nm;
        }
        __syncthreads();
    }
}

// ---------------------------------------------------------------------------
// k3: per (b,s) row of 1024: two-pass layernorm over d, scale by gs,
//     add residual x, clip to [0,1]. In-place on d_out.
// ---------------------------------------------------------------------------
__global__ __launch_bounds__(256, 1) void k3_norm(
        const float* __restrict__ x, const float* __restrict__ gs,
        float* __restrict__ y) {
    const int row = blockIdx.x;           // b*SEQ + s
    const int t   = threadIdx.x;
    const size_t base = (size_t)row * D_MODEL + t * 4;

    float4 yv = *(const float4*)(y + base);
    float s1 = (yv.x + yv.y) + (yv.z + yv.w);
#pragma unroll
    for (int off = 32; off > 0; off >>= 1) s1 += __shfl_xor(s1, off);

    __shared__ float red[8];
    const int w = t >> 6;
    if ((t & 63) == 0) red[w] = s1;
    __syncthreads();
    const float mu = (red[0] + red[1] + red[2] + red[3]) * (1.0f / (float)D_MODEL);

    const float dx0 = yv.x - mu, dx1 = yv.y - mu, dx2 = yv.z - mu, dx3 = yv.w - mu;
    float s2 = (dx0 * dx0 + dx1 * dx1) + (dx2 * dx2 + dx3 * dx3);
#pragma unroll
    for (int off = 32; off > 0; off >>= 1) s2 += __shfl_xor(s2, off);
    if ((t & 63) == 0) red[4 + w] = s2;
    __syncthreads();
    const float var = (red[4] + red[5] + red[6] + red[7]) * (1.0f / (float)D_MODEL);
    const float rs  = 1.0f / sqrtf(var + 1e-5f);

    float4 gv = *(const float4*)(gs + t * 4);
    float4 xv = *(const float4*)(x + base);
    float4 o;
    o.x = fminf(fmaxf(dx0 * rs * gv.x + xv.x, 0.f), 1.f);
    o.y = fminf(fmaxf(dx1 * rs * gv.y + xv.y, 0.f), 1.f);
    o.z = fminf(fmaxf(dx2 * rs * gv.z + xv.z, 0.f), 1.f);
    o.w = fminf(fmaxf(dx3 * rs * gv.w + xv.w, 0.f), 1.f);
    *(float4*)(y + base) = o;
}

// ---------------------------------------------------------------------------
extern "C" void kernel_launch(void* const* d_in, const int* in_sizes, int n_in,
                              void* d_out, int out_size, void* d_ws, size_t ws_size,
                              hipStream_t stream) {
    (void)in_sizes; (void)n_in; (void)out_size; (void)ws_size;
    const float* x     = (const float*)d_in[0];
    const float* A     = (const float*)d_in[1];
    const float* W_B   = (const float*)d_in[2];
    const float* W_C   = (const float*)d_in[3];
    const float* gamma = (const float*)d_in[4];
    float* out = (float*)d_out;
    float* ws  = (float*)d_ws;

    float* bt    = ws;                                  // 16384*64 = 1048576 floats
    float* A_sig = ws + 1048576;                        // 65536
    float* BwT   = ws + 1048576 + 65536;                // 65536
    float* Cs    = ws + 1048576 + 2 * 65536;            // 65536
    float* gs    = ws + 1048576 + 3 * 65536;            // 1024
    float* btmin = ws + 1048576 + 3 * 65536 + 1024;     // 16384

    k0_precompute<<<dim3(256), dim3(256), 0, stream>>>(A, W_B, W_C, gamma,
                                                       A_sig, BwT, Cs, gs);
    k1_bt_gemm<<<dim3(512), dim3(256), 0, stream>>>(x, BwT, bt, btmin);
    k2_scan<<<dim3(2048), dim3(256), 0, stream>>>(x, bt, btmin, A_sig, Cs, out);
    k3_norm<<<dim3(BATCH * SEQ), dim3(256), 0, stream>>>(x, gs, out);
}

// Round 3
// 234.666 us; speedup vs baseline: 1.8145x; 1.8145x over previous
//
#include <hip/hip_runtime.h>
#include <math.h>

#define D_MODEL 1024
#define N_STATE 64
#define BATCH   16
#define SEQ     1024
#define CS      16          // scan steps per LDS chunk
#define SEGLEN  512         // steps stored per segment
#define WARM    64          // warmup steps for segment 1 (0.7311^64 ~ 2e-9)
#define SAT_T   1.0001f     // saturation margin (covers fp32 rounding)

__device__ __forceinline__ float sigmoidf_dev(float v) {
    return 1.0f / (1.0f + expf(-v));
}

// DPP add: v += v[partner] within an aligned 16-lane row. Pure VALU, no LDS.
// 0xB1 = quad_perm [1,0,3,2] (xor1), 0x4E = quad_perm [2,3,0,1] (xor2),
// 0x141 = row_half_mirror (acts as xor4 on quad-uniform values),
// 0x140 = row_mirror (acts as xor8 on half-row-uniform values).
template<int CTRL>
__device__ __forceinline__ float dpp_add(float v) {
    int s = __builtin_amdgcn_update_dpp(0, __float_as_int(v), CTRL, 0xF, 0xF, true);
    return v + __int_as_float(s);
}

template<int CTRL>
__device__ __forceinline__ float dpp_min(float v) {
    int s = __builtin_amdgcn_update_dpp(0, __float_as_int(v), CTRL, 0xF, 0xF, true);
    return fminf(v, __int_as_float(s));
}

#define CLAMP01(v) __builtin_amdgcn_fmed3f((v), 0.0f, 1.0f)

// ---------------------------------------------------------------------------
// k0: precompute sigmoid(A) [D,N], sigmoid(W_B)^T -> BwT [D,N],
//     sigmoid(W_C) [D,N], sigmoid(gamma) [D]
// ---------------------------------------------------------------------------
__global__ __launch_bounds__(256) void k0_precompute(
        const float* __restrict__ A, const float* __restrict__ W_B,
        const float* __restrict__ W_C, const float* __restrict__ gamma,
        float* __restrict__ A_sig, float* __restrict__ BwT,
        float* __restrict__ Cs, float* __restrict__ gs) {
    int i = blockIdx.x * 256 + threadIdx.x;
    if (i < D_MODEL * N_STATE) {
        A_sig[i] = sigmoidf_dev(A[i]);
        Cs[i]    = sigmoidf_dev(W_C[i]);
        int d = i >> 6, n = i & 63;                  // i = d*64 + n
        BwT[i] = sigmoidf_dev(W_B[n * D_MODEL + d]); // W_B is [N, D]
        if (i < D_MODEL) gs[i] = sigmoidf_dev(gamma[i]);
    }
}

// ---------------------------------------------------------------------------
// k0b: csum[d] = sum_n Cs[d][n], in EXACTLY the op order of k2's slow path
// with h==1: per-quad (c0+c1)+(c2+c3), then balanced XOR tree off=1,2,4,8
// over the 16 quad sums (replicates the DPP tree bitwise). k3 substitutes
// csum[d] for every saturated element, so bit-match with k2's slow path
// keeps the final output bitwise identical to rounds 0/1.
// ---------------------------------------------------------------------------
__global__ __launch_bounds__(256) void k0b_csum(
        const float* __restrict__ Cs, float* __restrict__ csum) {
    int d = blockIdx.x * 256 + threadIdx.x;
    if (d >= D_MODEL) return;
    const float4* c = (const float4*)(Cs + (size_t)d * N_STATE);
    float w[16];
#pragma unroll
    for (int q = 0; q < 16; ++q) {
        float4 v = c[q];
        w[q] = (v.x + v.y) + (v.z + v.w);
    }
#pragma unroll
    for (int off = 1; off < 16; off <<= 1) {
        float tmp[16];
#pragma unroll
        for (int q = 0; q < 16; ++q) tmp[q] = w[q] + w[q ^ off];
#pragma unroll
        for (int q = 0; q < 16; ++q) w[q] = tmp[q];
    }
    csum[d] = w[0];
}

// ---------------------------------------------------------------------------
// k1: bt[m][n] = sum_d x[m][d] * BwT[d][n]  (M=16384, K=1024, N=64, fp32)
// grid 512 (2 blocks/CU), block 256. Mtile=32, Ntile=64, Ktile=32.
// 8 outputs/thread (2m x 4n). Double-buffered LDS + register prefetch.
// Epilogue emits btmin[m] = min_n bt[m][n] (DPP row-min) for the
// saturation fast path in k2/k3.
// ---------------------------------------------------------------------------
__global__ __launch_bounds__(256) void k1_bt_gemm(
        const float* __restrict__ x, const float* __restrict__ BwT,
        float* __restrict__ bt, float* __restrict__ btmin) {
    __shared__ float xs[2][32][34];   // [buf][k][m], +2 pad
    __shared__ float bs[2][32][64];   // [buf][k][n]

    const int t  = threadIdx.x;
    const int r  = t >> 4;            // 0..15 -> m rows r*2, r*2+1
    const int c  = t & 15;            // 0..15 -> n quad c*4
    const int m0 = blockIdx.x * 32;

    const int mr  = t >> 3;           // 0..31 (x staging row)
    const int kc4 = (t & 7) * 4;      // 0..28 (x staging k quad)

    float acc[2][4];
#pragma unroll
    for (int i = 0; i < 2; ++i)
#pragma unroll
        for (int j = 0; j < 4; ++j) acc[i][j] = 0.0f;

    {
        float4 xv = *(const float4*)(x + (size_t)(m0 + mr) * D_MODEL + kc4);
        float4 b0 = *(const float4*)(BwT + t * 4);
        float4 b1 = *(const float4*)(BwT + 1024 + t * 4);
        xs[0][kc4 + 0][mr] = xv.x;
        xs[0][kc4 + 1][mr] = xv.y;
        xs[0][kc4 + 2][mr] = xv.z;
        xs[0][kc4 + 3][mr] = xv.w;
        *(float4*)(&bs[0][0][0] + t * 4)        = b0;
        *(float4*)(&bs[0][0][0] + 1024 + t * 4) = b1;
    }
    __syncthreads();

    for (int kc = 0; kc < 32; ++kc) {
        const int p = kc & 1;
        float4 xv, b0, b1;
        const bool more = (kc + 1 < 32);
        if (more) {
            const int k0 = (kc + 1) * 32;
            xv = *(const float4*)(x + (size_t)(m0 + mr) * D_MODEL + k0 + kc4);
            b0 = *(const float4*)(BwT + (size_t)k0 * N_STATE + t * 4);
            b1 = *(const float4*)(BwT + (size_t)k0 * N_STATE + 1024 + t * 4);
        }
#pragma unroll
        for (int kk = 0; kk < 32; ++kk) {
            float2 ap = *(const float2*)(&xs[p][kk][r * 2]);
            float4 bq = *(const float4*)(&bs[p][kk][c * 4]);
            acc[0][0] = fmaf(ap.x, bq.x, acc[0][0]);
            acc[0][1] = fmaf(ap.x, bq.y, acc[0][1]);
            acc[0][2] = fmaf(ap.x, bq.z, acc[0][2]);
            acc[0][3] = fmaf(ap.x, bq.w, acc[0][3]);
            acc[1][0] = fmaf(ap.y, bq.x, acc[1][0]);
            acc[1][1] = fmaf(ap.y, bq.y, acc[1][1]);
            acc[1][2] = fmaf(ap.y, bq.z, acc[1][2]);
            acc[1][3] = fmaf(ap.y, bq.w, acc[1][3]);
        }
        if (more) {
            const int q = 1 - p;
            xs[q][kc4 + 0][mr] = xv.x;
            xs[q][kc4 + 1][mr] = xv.y;
            xs[q][kc4 + 2][mr] = xv.z;
            xs[q][kc4 + 3][mr] = xv.w;
            *(float4*)(&bs[q][0][0] + t * 4)        = b0;
            *(float4*)(&bs[q][0][0] + 1024 + t * 4) = b1;
        }
        __syncthreads();
    }

#pragma unroll
    for (int i = 0; i < 2; ++i) {
        float4 o = make_float4(acc[i][0], acc[i][1], acc[i][2], acc[i][3]);
        *(float4*)(&bt[(size_t)(m0 + r * 2 + i) * N_STATE + c * 4]) = o;
    }

    // btmin epilogue: per-thread min of its 4 n's, then DPP row-min over the
    // 16 lanes sharing r (aligned 16-lane rows within the wave).
    float bm0 = fminf(fminf(acc[0][0], acc[0][1]), fminf(acc[0][2], acc[0][3]));
    float bm1 = fminf(fminf(acc[1][0], acc[1][1]), fminf(acc[1][2], acc[1][3]));
    bm0 = dpp_min<0xB1>(bm0); bm0 = dpp_min<0x4E>(bm0);
    bm0 = dpp_min<0x141>(bm0); bm0 = dpp_min<0x140>(bm0);
    bm1 = dpp_min<0xB1>(bm1); bm1 = dpp_min<0x4E>(bm1);
    bm1 = dpp_min<0x141>(bm1); bm1 = dpp_min<0x140>(bm1);
    if (c == 0) {
        btmin[m0 + r * 2]     = bm0;
        btmin[m0 + r * 2 + 1] = bm1;
    }
}

// ---------------------------------------------------------------------------
// k2: sequential scan, time-segmented 2x. grid 2048 = 16 batch x 64 dgroup x
// 2 segments -> 8 blocks/CU, 32 waves/CU.
// Saturation fast path: pred(s,d) = x[s][d]*max(btmin[s],0) >= SAT_T implies
// every h-state clamps to exactly 1.0f (bv_n*x >= btmin*x >= SAT_T for all n,
// monotone fp rounding), so the step's y is bitwise csum[d]. pred is
// recomputable in k3 from x + btmin, so k2 stores NOTHING for saturated
// elements (~99.6%) — this removes the round-1 partial-line write storm
// (WRITE_SIZE 454 MB -> ~1 MB). Slow (pred-false) elements run the exact
// original update + straight DPP tree and store scattered 4B (~0.4%).
// px = x*bm is premultiplied into LDS at staging: a fast step costs one
// broadcast LDS read + cmp + wave vote.
// ---------------------------------------------------------------------------
__global__ __launch_bounds__(256, 8) void k2_scan(
        const float* __restrict__ x, const float* __restrict__ bt,
        const float* __restrict__ btmin,
        const float* __restrict__ A_sig, const float* __restrict__ Cs,
        float* __restrict__ y_raw) {
    const int t    = threadIdx.x;
    const int lane = t & 63;
    const int wv   = t >> 6;
    const int nq   = lane & 15;            // n-quad -> n = nq*4
    const int cl   = wv * 4 + (lane >> 4); // chain within block, 0..15
    const int bid  = blockIdx.x;
    const int seg  = bid & 1;
    const int dg   = (bid >> 1) & 63;
    const int b    = bid >> 7;
    const int d0   = dg * 16;
    const int d    = d0 + cl;

    const int nWarm  = seg ? (WARM / CS) : 0;     // 4 or 0
    const int nTot   = nWarm + (SEGLEN / CS);     // 36 or 32
    const int sStart = seg * SEGLEN - nWarm * CS; // 0 or 448

    __shared__ __align__(16) float lbt[2][CS * 64];   // 2 x 4 KB bt tile
    __shared__ __align__(16) float lx [2][CS * 16];   // 2 x 1 KB  x[step][chain]
    __shared__ __align__(16) float lpx[2][CS * 16];   // 2 x 1 KB  x*bm[step][chain]

    const float4 av = *(const float4*)(A_sig + (size_t)d * N_STATE + nq * 4);
    const float4 cv = *(const float4*)(Cs    + (size_t)d * N_STATE + nq * 4);

    float h0 = 0.f, h1 = 0.f, h2 = 0.f, h3 = 0.f;

    const float* btp  = bt    + (size_t)b * SEQ * N_STATE + (size_t)sStart * N_STATE;
    const float* btmp = btmin + (size_t)b * SEQ + sStart;
    const float* xpp  = x + (size_t)b * SEQ * D_MODEL + (size_t)sStart * D_MODEL + d0;
    float* ystore = y_raw + (size_t)b * SEQ * D_MODEL + (size_t)seg * SEGLEN * D_MODEL + d;

    const int xst = t >> 4;          // staging: step 0..15
    const int xdd = t & 15;          // staging: chain

    // stage chunk 0 into buf 0
    {
        float4 b4 = *(const float4*)(btp + t * 4);
        float  xv = xpp[(size_t)xst * D_MODEL + xdd];
        float  bm = fmaxf(btmp[xst], 0.f);   // clamp: pred => bm>0 and x>0
        *(float4*)(&lbt[0][t * 4]) = b4;
        lx [0][t] = xv;
        lpx[0][t] = xv * bm;
    }
    btp  += CS * N_STATE;
    btmp += CS;
    xpp  += (size_t)CS * D_MODEL;
    __syncthreads();

    for (int ch = 0; ch < nTot; ++ch) {
        const int p = ch & 1;
        float4 nb; float nx, npx;
        const bool more = (ch + 1 < nTot);
        if (more) {
            nb  = *(const float4*)(btp + t * 4);
            nx  = xpp[(size_t)xst * D_MODEL + xdd];
            npx = nx * fmaxf(btmp[xst], 0.f);
            btp  += CS * N_STATE;
            btmp += CS;
            xpp  += (size_t)CS * D_MODEL;
        }

        const float* Lb = lbt[p];
        const float* Lx = lx [p];
        const float* Lp = lpx[p];

        if (ch < nWarm) {
#pragma unroll
            for (int i = 0; i < CS; ++i) {
                const float pm = Lp[i * 16 + cl];
                if (__all(pm >= SAT_T)) { h0 = h1 = h2 = h3 = 1.f; continue; }
                const float  xt = Lx[i * 16 + cl];
                const float4 bv = *(const float4*)(Lb + i * 64 + nq * 4);
                h0 = CLAMP01(fmaf(h0, av.x, bv.x * xt));
                h1 = CLAMP01(fmaf(h1, av.y, bv.y * xt));
                h2 = CLAMP01(fmaf(h2, av.z, bv.z * xt));
                h3 = CLAMP01(fmaf(h3, av.w, bv.w * xt));
            }
        } else {
#pragma unroll
            for (int i = 0; i < CS; ++i) {
                const float pm = Lp[i * 16 + cl];
                if (__all(pm >= SAT_T)) { h0 = h1 = h2 = h3 = 1.f; continue; }
                const float  xt = Lx[i * 16 + cl];
                const float4 bv = *(const float4*)(Lb + i * 64 + nq * 4);
                h0 = CLAMP01(fmaf(h0, av.x, bv.x * xt));
                h1 = CLAMP01(fmaf(h1, av.y, bv.y * xt));
                h2 = CLAMP01(fmaf(h2, av.z, bv.z * xt));
                h3 = CLAMP01(fmaf(h3, av.w, bv.w * xt));
                float y = fmaf(h0, cv.x, h1 * cv.y) + fmaf(h2, cv.z, h3 * cv.w);
                y = dpp_add<0xB1>(y);
                y = dpp_add<0x4E>(y);
                y = dpp_add<0x141>(y);
                y = dpp_add<0x140>(y);
                // store only pred-false elements (row-uniform condition);
                // pred-true rows are reconstructed as csum[d] in k3.
                if (nq == 0 && !(pm >= SAT_T)) ystore[(size_t)i * D_MODEL] = y;
            }
            ystore += (size_t)CS * D_MODEL;
        }

        if (more) {
            const int q = 1 - p;
            *(float4*)(&lbt[q][t * 4]) = nb;
            lx [q][t] = nx;
            lpx[q][t] = npx;
        }
        __syncthreads();
    }
}

// ---------------------------------------------------------------------------
// k3: per (b,s) row of 1024: reconstruct y (pred ? csum[d] : stored y_raw),
// two-pass layernorm over d, scale by gs, add residual x, clip. In-place.
// ---------------------------------------------------------------------------
__global__ __launch_bounds__(256, 1) void k3_norm(
        const float* __restrict__ x, const float* __restrict__ gs,
        const float* __restrict__ btmin, const float* __restrict__ csum,
        float* __restrict__ y) {
    const int row = blockIdx.x;           // b*SEQ + s
    const int t   = threadIdx.x;
    const size_t base = (size_t)row * D_MODEL + t * 4;
    const float bm = fmaxf(btmin[row], 0.f);   // same clamp+product as k2

    float4 xv  = *(const float4*)(x + base);
    float4 cs4 = *(const float4*)(csum + t * 4);
    float y0 = cs4.x, y1 = cs4.y, y2 = cs4.z, y3 = cs4.w;
    if (!(xv.x * bm >= SAT_T)) y0 = y[base + 0];
    if (!(xv.y * bm >= SAT_T)) y1 = y[base + 1];
    if (!(xv.z * bm >= SAT_T)) y2 = y[base + 2];
    if (!(xv.w * bm >= SAT_T)) y3 = y[base + 3];

    float s1 = (y0 + y1) + (y2 + y3);
#pragma unroll
    for (int off = 32; off > 0; off >>= 1) s1 += __shfl_xor(s1, off);

    __shared__ float red[8];
    const int w = t >> 6;
    if ((t & 63) == 0) red[w] = s1;
    __syncthreads();
    const float mu = (red[0] + red[1] + red[2] + red[3]) * (1.0f / (float)D_MODEL);

    const float dx0 = y0 - mu, dx1 = y1 - mu, dx2 = y2 - mu, dx3 = y3 - mu;
    float s2 = (dx0 * dx0 + dx1 * dx1) + (dx2 * dx2 + dx3 * dx3);
#pragma unroll
    for (int off = 32; off > 0; off >>= 1) s2 += __shfl_xor(s2, off);
    if ((t & 63) == 0) red[4 + w] = s2;
    __syncthreads();
    const float var = (red[4] + red[5] + red[6] + red[7]) * (1.0f / (float)D_MODEL);
    const float rs  = 1.0f / sqrtf(var + 1e-5f);

    float4 gv = *(const float4*)(gs + t * 4);
    float4 o;
    o.x = fminf(fmaxf(dx0 * rs * gv.x + xv.x, 0.f), 1.f);
    o.y = fminf(fmaxf(dx1 * rs * gv.y + xv.y, 0.f), 1.f);
    o.z = fminf(fmaxf(dx2 * rs * gv.z + xv.z, 0.f), 1.f);
    o.w = fminf(fmaxf(dx3 * rs * gv.w + xv.w, 0.f), 1.f);
    *(float4*)(y + base) = o;
}

// ---------------------------------------------------------------------------
extern "C" void kernel_launch(void* const* d_in, const int* in_sizes, int n_in,
                              void* d_out, int out_size, void* d_ws, size_t ws_size,
                              hipStream_t stream) {
    (void)in_sizes; (void)n_in; (void)out_size; (void)ws_size;
    const float* x     = (const float*)d_in[0];
    const float* A     = (const float*)d_in[1];
    const float* W_B   = (const float*)d_in[2];
    const float* W_C   = (const float*)d_in[3];
    const float* gamma = (const float*)d_in[4];
    float* out = (float*)d_out;
    float* ws  = (float*)d_ws;

    float* bt    = ws;                                       // 1048576 floats
    float* A_sig = ws + 1048576;                             // 65536
    float* BwT   = ws + 1048576 + 65536;                     // 65536
    float* Cs    = ws + 1048576 + 2 * 65536;                 // 65536
    float* gs    = ws + 1048576 + 3 * 65536;                 // 1024
    float* btmin = ws + 1048576 + 3 * 65536 + 1024;          // 16384
    float* csum  = ws + 1048576 + 3 * 65536 + 1024 + 16384;  // 1024

    k0_precompute<<<dim3(256), dim3(256), 0, stream>>>(A, W_B, W_C, gamma,
                                                       A_sig, BwT, Cs, gs);
    k0b_csum<<<dim3(4), dim3(256), 0, stream>>>(Cs, csum);
    k1_bt_gemm<<<dim3(512), dim3(256), 0, stream>>>(x, BwT, bt, btmin);
    k2_scan<<<dim3(2048), dim3(256), 0, stream>>>(x, bt, btmin, A_sig, Cs, out);
    k3_norm<<<dim3(BATCH * SEQ), dim3(256), 0, stream>>>(x, gs, btmin, csum, out);
}

// Round 4
// 231.786 us; speedup vs baseline: 1.8371x; 1.0124x over previous
//
#include <hip/hip_runtime.h>
#include <math.h>

#define D_MODEL 1024
#define N_STATE 64
#define BATCH   16
#define SEQ     1024
#define CS      16          // scan steps per LDS chunk
#define SEGLEN  512         // steps stored per segment
#define WARM    64          // warmup steps for segment 1 (0.7311^64 ~ 2e-9)
#define SAT_T   1.0001f     // saturation margin (covers fp32 rounding)
#define LPS     20          // lpxT row stride (pad: 20 coprime-ish w/ 32 banks, 16B-aligned rows)

__device__ __forceinline__ float sigmoidf_dev(float v) {
    return 1.0f / (1.0f + expf(-v));
}

// DPP add: v += v[partner] within an aligned 16-lane row. Pure VALU, no LDS.
// 0xB1 = quad_perm [1,0,3,2] (xor1), 0x4E = quad_perm [2,3,0,1] (xor2),
// 0x141 = row_half_mirror (acts as xor4 on quad-uniform values),
// 0x140 = row_mirror (acts as xor8 on half-row-uniform values).
template<int CTRL>
__device__ __forceinline__ float dpp_add(float v) {
    int s = __builtin_amdgcn_update_dpp(0, __float_as_int(v), CTRL, 0xF, 0xF, true);
    return v + __int_as_float(s);
}

template<int CTRL>
__device__ __forceinline__ float dpp_min(float v) {
    int s = __builtin_amdgcn_update_dpp(0, __float_as_int(v), CTRL, 0xF, 0xF, true);
    return fminf(v, __int_as_float(s));
}

#define CLAMP01(v) __builtin_amdgcn_fmed3f((v), 0.0f, 1.0f)

// ---------------------------------------------------------------------------
// k0: precompute sigmoid(A) [D,N], sigmoid(W_B)^T -> BwT [D,N],
//     sigmoid(W_C) [D,N], sigmoid(gamma) [D]
// ---------------------------------------------------------------------------
__global__ __launch_bounds__(256) void k0_precompute(
        const float* __restrict__ A, const float* __restrict__ W_B,
        const float* __restrict__ W_C, const float* __restrict__ gamma,
        float* __restrict__ A_sig, float* __restrict__ BwT,
        float* __restrict__ Cs, float* __restrict__ gs) {
    int i = blockIdx.x * 256 + threadIdx.x;
    if (i < D_MODEL * N_STATE) {
        A_sig[i] = sigmoidf_dev(A[i]);
        Cs[i]    = sigmoidf_dev(W_C[i]);
        int d = i >> 6, n = i & 63;                  // i = d*64 + n
        BwT[i] = sigmoidf_dev(W_B[n * D_MODEL + d]); // W_B is [N, D]
        if (i < D_MODEL) gs[i] = sigmoidf_dev(gamma[i]);
    }
}

// ---------------------------------------------------------------------------
// k0b: csum[d] = sum_n Cs[d][n], in EXACTLY the op order of k2's slow path
// with h==1: per-quad (c0+c1)+(c2+c3), then balanced XOR tree off=1,2,4,8
// over the 16 quad sums (replicates the DPP tree bitwise). k3 substitutes
// csum[d] for every saturated element, so bit-match with k2's slow path
// keeps the final output bitwise identical.
// ---------------------------------------------------------------------------
__global__ __launch_bounds__(256) void k0b_csum(
        const float* __restrict__ Cs, float* __restrict__ csum) {
    int d = blockIdx.x * 256 + threadIdx.x;
    if (d >= D_MODEL) return;
    const float4* c = (const float4*)(Cs + (size_t)d * N_STATE);
    float w[16];
#pragma unroll
    for (int q = 0; q < 16; ++q) {
        float4 v = c[q];
        w[q] = (v.x + v.y) + (v.z + v.w);
    }
#pragma unroll
    for (int off = 1; off < 16; off <<= 1) {
        float tmp[16];
#pragma unroll
        for (int q = 0; q < 16; ++q) tmp[q] = w[q] + w[q ^ off];
#pragma unroll
        for (int q = 0; q < 16; ++q) w[q] = tmp[q];
    }
    csum[d] = w[0];
}

// ---------------------------------------------------------------------------
// k1: bt[m][n] = sum_d x[m][d] * BwT[d][n]  (M=16384, K=1024, N=64, fp32)
// Mtile=16, Ntile=64, Ktile=32 -> grid 1024 (4 blocks/CU, 16 waves/CU for
// latency hiding; round-3 version ran only 2 blocks/CU). 4 outputs/thread
// (1m x 4n). K-iteration order (kc,kk) identical to round 3 -> bt bitwise
// identical. Double-buffered LDS + register prefetch.
// Epilogue emits btmin[m] = min_n bt[m][n] (DPP row-min).
// ---------------------------------------------------------------------------
__global__ __launch_bounds__(256) void k1_bt_gemm(
        const float* __restrict__ x, const float* __restrict__ BwT,
        float* __restrict__ bt, float* __restrict__ btmin) {
    __shared__ float xs[2][32][17];   // [buf][k][m], +1 pad (2-way max on write)
    __shared__ float bs[2][32][64];   // [buf][k][n]

    const int t  = threadIdx.x;
    const int r  = t >> 4;            // 0..15 -> m row
    const int c  = t & 15;            // 0..15 -> n quad c*4
    const int m0 = blockIdx.x * 16;

    const int xr = t >> 4;            // x staging row 0..15
    const int xk = (t & 15) * 2;      // x staging k pair 0..30

    float acc[4] = {0.f, 0.f, 0.f, 0.f};

    {
        float2 xv = *(const float2*)(x + (size_t)(m0 + xr) * D_MODEL + xk);
        float4 b0 = *(const float4*)(BwT + t * 4);
        float4 b1 = *(const float4*)(BwT + 1024 + t * 4);
        xs[0][xk + 0][xr] = xv.x;
        xs[0][xk + 1][xr] = xv.y;
        *(float4*)(&bs[0][0][0] + t * 4)        = b0;
        *(float4*)(&bs[0][0][0] + 1024 + t * 4) = b1;
    }
    __syncthreads();

    for (int kc = 0; kc < 32; ++kc) {
        const int p = kc & 1;
        float2 xv; float4 b0, b1;
        const bool more = (kc + 1 < 32);
        if (more) {
            const int k0 = (kc + 1) * 32;
            xv = *(const float2*)(x + (size_t)(m0 + xr) * D_MODEL + k0 + xk);
            b0 = *(const float4*)(BwT + (size_t)k0 * N_STATE + t * 4);
            b1 = *(const float4*)(BwT + (size_t)k0 * N_STATE + 1024 + t * 4);
        }
#pragma unroll
        for (int kk = 0; kk < 32; ++kk) {
            float  a  = xs[p][kk][r];
            float4 bq = *(const float4*)(&bs[p][kk][c * 4]);
            acc[0] = fmaf(a, bq.x, acc[0]);
            acc[1] = fmaf(a, bq.y, acc[1]);
            acc[2] = fmaf(a, bq.z, acc[2]);
            acc[3] = fmaf(a, bq.w, acc[3]);
        }
        if (more) {
            const int q = 1 - p;
            xs[q][xk + 0][xr] = xv.x;
            xs[q][xk + 1][xr] = xv.y;
            *(float4*)(&bs[q][0][0] + t * 4)        = b0;
            *(float4*)(&bs[q][0][0] + 1024 + t * 4) = b1;
        }
        __syncthreads();
    }

    *(float4*)(&bt[(size_t)(m0 + r) * N_STATE + c * 4]) =
        make_float4(acc[0], acc[1], acc[2], acc[3]);

    // btmin: per-thread min of its 4 n's, then DPP min across the aligned
    // 16-lane row (lanes sharing r).
    float bm = fminf(fminf(acc[0], acc[1]), fminf(acc[2], acc[3]));
    bm = dpp_min<0xB1>(bm); bm = dpp_min<0x4E>(bm);
    bm = dpp_min<0x141>(bm); bm = dpp_min<0x140>(bm);
    if (c == 0) btmin[m0 + r] = bm;
}

// ---------------------------------------------------------------------------
// k2: sequential scan, time-segmented 2x. grid 2048 = 16 batch x 64 dgroup x
// 2 segments -> 8 blocks/CU, 32 waves/CU.
// Saturation fast path (round-3, verified): pred(s,d) = x*max(btmin,0) >=
// SAT_T => h clamps to exactly 1.0f, y bitwise csum[d]; k2 stores only
// pred-false rows (~0.4%), k3 reconstructs the rest.
// NEW (round 4): px stored transposed [chain][LPS]; the step loop processes
// 4-step groups with ONE float4 read + 3 min + 1 vote when the wave's quad
// is all-fast (~94%), falling back to the identical per-step path (same
// float4 components -> bitwise-same predicate) for mixed quads.
// ---------------------------------------------------------------------------
__global__ __launch_bounds__(256, 8) void k2_scan(
        const float* __restrict__ x, const float* __restrict__ bt,
        const float* __restrict__ btmin,
        const float* __restrict__ A_sig, const float* __restrict__ Cs,
        float* __restrict__ y_raw) {
    const int t    = threadIdx.x;
    const int lane = t & 63;
    const int wv   = t >> 6;
    const int nq   = lane & 15;            // n-quad -> n = nq*4
    const int cl   = wv * 4 + (lane >> 4); // chain within block, 0..15
    const int bid  = blockIdx.x;
    const int seg  = bid & 1;
    const int dg   = (bid >> 1) & 63;
    const int b    = bid >> 7;
    const int d0   = dg * 16;
    const int d    = d0 + cl;

    const int nWarm  = seg ? (WARM / CS) : 0;     // 4 or 0
    const int nTot   = nWarm + (SEGLEN / CS);     // 36 or 32
    const int sStart = seg * SEGLEN - nWarm * CS; // 0 or 448

    __shared__ __align__(16) float lbt [2][CS * 64];    // 2 x 4 KB bt tile
    __shared__ __align__(16) float lx  [2][CS * 16];    // 2 x 1 KB x[step][chain]
    __shared__ __align__(16) float lpxT[2][16 * LPS];   // 2 x 1.25 KB px[chain][step(+pad)]

    const float4 av = *(const float4*)(A_sig + (size_t)d * N_STATE + nq * 4);
    const float4 cv = *(const float4*)(Cs    + (size_t)d * N_STATE + nq * 4);

    float h0 = 0.f, h1 = 0.f, h2 = 0.f, h3 = 0.f;

    const float* btp  = bt    + (size_t)b * SEQ * N_STATE + (size_t)sStart * N_STATE;
    const float* btmp = btmin + (size_t)b * SEQ + sStart;
    const float* xpp  = x + (size_t)b * SEQ * D_MODEL + (size_t)sStart * D_MODEL + d0;
    float* ystore = y_raw + (size_t)b * SEQ * D_MODEL + (size_t)seg * SEGLEN * D_MODEL + d;

    const int xst = t >> 4;          // staging: step 0..15
    const int xdd = t & 15;          // staging: chain

    // stage chunk 0 into buf 0
    {
        float4 b4 = *(const float4*)(btp + t * 4);
        float  xv = xpp[(size_t)xst * D_MODEL + xdd];
        float  bm = fmaxf(btmp[xst], 0.f);   // clamp: pred => bm>0 and x>0
        *(float4*)(&lbt[0][t * 4]) = b4;
        lx[0][t] = xv;
        lpxT[0][xdd * LPS + xst] = xv * bm;
    }
    btp  += CS * N_STATE;
    btmp += CS;
    xpp  += (size_t)CS * D_MODEL;
    __syncthreads();

    for (int ch = 0; ch < nTot; ++ch) {
        const int p = ch & 1;
        float4 nb; float nx, npx;
        const bool more = (ch + 1 < nTot);
        if (more) {
            nb  = *(const float4*)(btp + t * 4);
            nx  = xpp[(size_t)xst * D_MODEL + xdd];
            npx = nx * fmaxf(btmp[xst], 0.f);
            btp  += CS * N_STATE;
            btmp += CS;
            xpp  += (size_t)CS * D_MODEL;
        }

        const float* Lb = lbt[p];
        const float* Lx = lx [p];
        const float* Lp = &lpxT[p][cl * LPS];   // this lane's chain, 16 steps

        if (ch < nWarm) {
#pragma unroll
            for (int g = 0; g < 4; ++g) {
                const float4 pq = *(const float4*)(Lp + g * 4);
                const float qmin = fminf(fminf(pq.x, pq.y), fminf(pq.z, pq.w));
                if (__all(qmin >= SAT_T)) { h0 = h1 = h2 = h3 = 1.f; continue; }
                const float pmv[4] = {pq.x, pq.y, pq.z, pq.w};
#pragma unroll
                for (int j = 0; j < 4; ++j) {
                    const int i = g * 4 + j;
                    const float pm = pmv[j];
                    if (__all(pm >= SAT_T)) { h0 = h1 = h2 = h3 = 1.f; continue; }
                    const float  xt = Lx[i * 16 + cl];
                    const float4 bv = *(const float4*)(Lb + i * 64 + nq * 4);
                    h0 = CLAMP01(fmaf(h0, av.x, bv.x * xt));
                    h1 = CLAMP01(fmaf(h1, av.y, bv.y * xt));
                    h2 = CLAMP01(fmaf(h2, av.z, bv.z * xt));
                    h3 = CLAMP01(fmaf(h3, av.w, bv.w * xt));
                }
            }
        } else {
#pragma unroll
            for (int g = 0; g < 4; ++g) {
                const float4 pq = *(const float4*)(Lp + g * 4);
                const float qmin = fminf(fminf(pq.x, pq.y), fminf(pq.z, pq.w));
                if (__all(qmin >= SAT_T)) { h0 = h1 = h2 = h3 = 1.f; continue; }
                const float pmv[4] = {pq.x, pq.y, pq.z, pq.w};
#pragma unroll
                for (int j = 0; j < 4; ++j) {
                    const int i = g * 4 + j;
                    const float pm = pmv[j];
                    if (__all(pm >= SAT_T)) { h0 = h1 = h2 = h3 = 1.f; continue; }
                    const float  xt = Lx[i * 16 + cl];
                    const float4 bv = *(const float4*)(Lb + i * 64 + nq * 4);
                    h0 = CLAMP01(fmaf(h0, av.x, bv.x * xt));
                    h1 = CLAMP01(fmaf(h1, av.y, bv.y * xt));
                    h2 = CLAMP01(fmaf(h2, av.z, bv.z * xt));
                    h3 = CLAMP01(fmaf(h3, av.w, bv.w * xt));
                    float y = fmaf(h0, cv.x, h1 * cv.y) + fmaf(h2, cv.z, h3 * cv.w);
                    y = dpp_add<0xB1>(y);
                    y = dpp_add<0x4E>(y);
                    y = dpp_add<0x141>(y);
                    y = dpp_add<0x140>(y);
                    // store only pred-false rows (row-uniform condition);
                    // pred-true rows are reconstructed as csum[d] in k3.
                    if (nq == 0 && !(pm >= SAT_T)) ystore[(size_t)i * D_MODEL] = y;
                }
            }
            ystore += (size_t)CS * D_MODEL;
        }

        if (more) {
            const int q = 1 - p;
            *(float4*)(&lbt[q][t * 4]) = nb;
            lx[q][t] = nx;
            lpxT[q][xdd * LPS + xst] = npx;
        }
        __syncthreads();
    }
}

// ---------------------------------------------------------------------------
// k3: per (b,s) row of 1024: reconstruct y (pred ? csum[d] : stored y_raw),
// two-pass layernorm over d, scale by gs, add residual x, clip. In-place.
// Round 4: single conditional float4 load (taken by ~1.6% of lanes) replaces
// the 4 divergent scalar loads.
// ---------------------------------------------------------------------------
__global__ __launch_bounds__(256, 1) void k3_norm(
        const float* __restrict__ x, const float* __restrict__ gs,
        const float* __restrict__ btmin, const float* __restrict__ csum,
        float* __restrict__ y) {
    const int row = blockIdx.x;           // b*SEQ + s
    const int t   = threadIdx.x;
    const size_t base = (size_t)row * D_MODEL + t * 4;
    const float bm = fmaxf(btmin[row], 0.f);   // same clamp+product as k2

    float4 xv  = *(const float4*)(x + base);
    float4 cs4 = *(const float4*)(csum + t * 4);
    const bool p0 = (xv.x * bm >= SAT_T);
    const bool p1 = (xv.y * bm >= SAT_T);
    const bool p2 = (xv.z * bm >= SAT_T);
    const bool p3 = (xv.w * bm >= SAT_T);
    float y0 = cs4.x, y1 = cs4.y, y2 = cs4.z, y3 = cs4.w;
    if (!(p0 && p1 && p2 && p3)) {
        float4 ld = *(const float4*)(y + base);
        if (!p0) y0 = ld.x;
        if (!p1) y1 = ld.y;
        if (!p2) y2 = ld.z;
        if (!p3) y3 = ld.w;
    }

    float s1 = (y0 + y1) + (y2 + y3);
#pragma unroll
    for (int off = 32; off > 0; off >>= 1) s1 += __shfl_xor(s1, off);

    __shared__ float red[8];
    const int w = t >> 6;
    if ((t & 63) == 0) red[w] = s1;
    __syncthreads();
    const float mu = (red[0] + red[1] + red[2] + red[3]) * (1.0f / (float)D_MODEL);

    const float dx0 = y0 - mu, dx1 = y1 - mu, dx2 = y2 - mu, dx3 = y3 - mu;
    float s2 = (dx0 * dx0 + dx1 * dx1) + (dx2 * dx2 + dx3 * dx3);
#pragma unroll
    for (int off = 32; off > 0; off >>= 1) s2 += __shfl_xor(s2, off);
    if ((t & 63) == 0) red[4 + w] = s2;
    __syncthreads();
    const float var = (red[4] + red[5] + red[6] + red[7]) * (1.0f / (float)D_MODEL);
    const float rs  = 1.0f / sqrtf(var + 1e-5f);

    float4 gv = *(const float4*)(gs + t * 4);
    float4 o;
    o.x = fminf(fmaxf(dx0 * rs * gv.x + xv.x, 0.f), 1.f);
    o.y = fminf(fmaxf(dx1 * rs * gv.y + xv.y, 0.f), 1.f);
    o.z = fminf(fmaxf(dx2 * rs * gv.z + xv.z, 0.f), 1.f);
    o.w = fminf(fmaxf(dx3 * rs * gv.w + xv.w, 0.f), 1.f);
    *(float4*)(y + base) = o;
}

// ---------------------------------------------------------------------------
extern "C" void kernel_launch(void* const* d_in, const int* in_sizes, int n_in,
                              void* d_out, int out_size, void* d_ws, size_t ws_size,
                              hipStream_t stream) {
    (void)in_sizes; (void)n_in; (void)out_size; (void)ws_size;
    const float* x     = (const float*)d_in[0];
    const float* A     = (const float*)d_in[1];
    const float* W_B   = (const float*)d_in[2];
    const float* W_C   = (const float*)d_in[3];
    const float* gamma = (const float*)d_in[4];
    float* out = (float*)d_out;
    float* ws  = (float*)d_ws;

    float* bt    = ws;                                       // 1048576 floats
    float* A_sig = ws + 1048576;                             // 65536
    float* BwT   = ws + 1048576 + 65536;                     // 65536
    float* Cs    = ws + 1048576 + 2 * 65536;                 // 65536
    float* gs    = ws + 1048576 + 3 * 65536;                 // 1024
    float* btmin = ws + 1048576 + 3 * 65536 + 1024;          // 16384
    float* csum  = ws + 1048576 + 3 * 65536 + 1024 + 16384;  // 1024

    k0_precompute<<<dim3(256), dim3(256), 0, stream>>>(A, W_B, W_C, gamma,
                                                       A_sig, BwT, Cs, gs);
    k0b_csum<<<dim3(4), dim3(256), 0, stream>>>(Cs, csum);
    k1_bt_gemm<<<dim3(1024), dim3(256), 0, stream>>>(x, BwT, bt, btmin);
    k2_scan<<<dim3(2048), dim3(256), 0, stream>>>(x, bt, btmin, A_sig, Cs, out);
    k3_norm<<<dim3(BATCH * SEQ), dim3(256), 0, stream>>>(x, gs, btmin, csum, out);
}